// Round 2
// baseline (276.942 us; speedup 1.0000x reference)
//
#include <hip/hip_runtime.h>
#include <hip/hip_bf16.h>

#define N_NODES 1536
#define NF 64
#define NOUT 64
#define FIN 65

typedef __bf16 bf16x8 __attribute__((ext_vector_type(8)));
typedef float f32x4 __attribute__((ext_vector_type(4)));

// One block: one row i, 128 columns j. Swapped-operand MFMA:
//   D[o][j] = sum_k W[o][k] * |feat[j][k]-feat[i][k]|
// so each lane's C/D quad (row=lg*4+r, col=l15) is 4 CONSECUTIVE output
// channels of one output row -> float4 stores (full 256B rows completed by
// back-to-back offset-immediate stores from the same wave).
__global__ __launch_bounds__(256, 2)
void edge_gcn_mfma(const float* __restrict__ feat,
                   const float* __restrict__ adj,
                   const float* __restrict__ W,
                   const float* __restrict__ b,
                   float* __restrict__ out)
{
    const int tid  = threadIdx.x;
    const int lane = tid & 63;
    const int wv   = tid >> 6;          // wave 0..3
    const int l15  = lane & 15;
    const int lg   = lane >> 4;         // 0..3

    const int i  = blockIdx.y;
    const int j0 = blockIdx.x * 128;
    const int jw = j0 + wv * 32;        // this wave's 32 output rows (j)

    // ---- A fragments: A[row=o][k] = W[o][k]; o = mo*16+l15, k = kk*32+lg*8+e
    bf16x8 afrag[2][4];                 // [kk][mo]
#pragma unroll
    for (int kk = 0; kk < 2; ++kk) {
#pragma unroll
        for (int mo = 0; mo < 4; ++mo) {
            const float* wp = W + (mo * 16 + l15) * FIN + kk * 32 + lg * 8;
#pragma unroll
            for (int e = 0; e < 8; ++e) afrag[kk][mo][e] = (__bf16)wp[e];
        }
    }

    // ---- feat[i] slices (same k map as B frags) ----
    float fi[2][8];
#pragma unroll
    for (int kk = 0; kk < 2; ++kk) {
        const float* fp = feat + i * NF + kk * 32 + lg * 8;
#pragma unroll
        for (int e = 0; e < 8; ++e) fi[kk][e] = fp[e];
    }

    f32x4 acc[4][2];                    // [mo][n]
#pragma unroll
    for (int mo = 0; mo < 4; ++mo)
#pragma unroll
        for (int n = 0; n < 2; ++n)
            acc[mo][n] = (f32x4){0.f, 0.f, 0.f, 0.f};

    // ---- main MFMA: B[k][col=j] = |feat[j][k] - feat[i][k]|, col = l15 ----
#pragma unroll
    for (int n = 0; n < 2; ++n) {
        const int j = jw + n * 16 + l15;
        const float* fjrow = feat + j * NF;
#pragma unroll
        for (int kk = 0; kk < 2; ++kk) {
            const float* fj = fjrow + kk * 32 + lg * 8;
            bf16x8 bfrag;
#pragma unroll
            for (int e = 0; e < 8; ++e)
                bfrag[e] = (__bf16)fabsf(fj[e] - fi[kk][e]);
#pragma unroll
            for (int mo = 0; mo < 4; ++mo)
                acc[mo][n] = __builtin_amdgcn_mfma_f32_16x16x32_bf16(
                    afrag[kk][mo], bfrag, acc[mo][n], 0, 0, 0);
        }
    }

    // ---- epilogue: + adj[i][j]*W[o][64] + b[o], exact f32; o = mo*16+lg*4+r
    float wl[4][4], bv[4][4];
#pragma unroll
    for (int mo = 0; mo < 4; ++mo) {
        const float* bp = b + mo * 16 + lg * 4;          // 4 consecutive
#pragma unroll
        for (int r = 0; r < 4; ++r) {
            bv[mo][r] = bp[r];
            wl[mo][r] = W[(mo * 16 + lg * 4 + r) * FIN + NF];
        }
    }

#pragma unroll
    for (int n = 0; n < 2; ++n) {
        const int j = jw + n * 16 + l15;
        const float av = adj[(size_t)i * N_NODES + j];
        float* op = out + ((size_t)i * N_NODES + j) * NOUT + lg * 4;
#pragma unroll
        for (int mo = 0; mo < 4; ++mo) {
            f32x4 v;
#pragma unroll
            for (int r = 0; r < 4; ++r)
                v[r] = acc[mo][n][r] + av * wl[mo][r] + bv[mo][r];
            *reinterpret_cast<f32x4*>(op + mo * 16) = v;
        }
    }
}

extern "C" void kernel_launch(void* const* d_in, const int* in_sizes, int n_in,
                              void* d_out, int out_size, void* d_ws, size_t ws_size,
                              hipStream_t stream) {
    const float* feat = (const float*)d_in[0];   // [1536][64]
    const float* adj  = (const float*)d_in[1];   // [1536][1536]
    const float* W    = (const float*)d_in[2];   // [64][65]
    const float* b    = (const float*)d_in[3];   // [64]
    float* out = (float*)d_out;                  // [1536*1536][64]

    dim3 grid(N_NODES / 128, N_NODES);
    dim3 block(256);
    edge_gcn_mfma<<<grid, block, 0, stream>>>(feat, adj, W, b, out);
}

// Round 3
// 195.642 us; speedup vs baseline: 1.4156x; 1.4156x over previous
//
#include <hip/hip_runtime.h>
#include <hip/hip_bf16.h>

#define N_NODES 1536
#define NF 64
#define NOUT 64
#define FIN 65
#define TI 8

typedef __bf16 bf16x8 __attribute__((ext_vector_type(8)));
typedef float f32x4 __attribute__((ext_vector_type(4)));

// One block: TI=8 i-rows x 128 j-cols. W fragments, feat[j] fragments and
// W[:,64]/bias live in registers across the i-loop, so the scattered L1
// gathers happen once per block instead of once per (i-block). The per-block
// cost is then dominated by its 256 KB output stream.
//   D[o][j] = sum_k W[o][k] * |feat[j][k]-feat[i][k]|  (swapped-operand MFMA)
__global__ __launch_bounds__(256, 2)
void edge_gcn_mfma(const float* __restrict__ feat,
                   const float* __restrict__ adj,
                   const float* __restrict__ W,
                   const float* __restrict__ b,
                   float* __restrict__ out)
{
    const int tid  = threadIdx.x;
    const int lane = tid & 63;
    const int wv   = tid >> 6;          // wave 0..3
    const int l15  = lane & 15;
    const int lg   = lane >> 4;         // 0..3

    const int i0 = blockIdx.y * TI;
    const int j0 = blockIdx.x * 128;
    const int jw = j0 + wv * 32;        // this wave's 32 j's

    // ---- A fragments (W): A[m=l15][k=kk*32+lg*8+e], m-tile mo. Once. ----
    bf16x8 afrag[2][4];                 // [kk][mo]
#pragma unroll
    for (int kk = 0; kk < 2; ++kk) {
#pragma unroll
        for (int mo = 0; mo < 4; ++mo) {
            const float* wp = W + (mo * 16 + l15) * FIN + kk * 32 + lg * 8;
#pragma unroll
            for (int e = 0; e < 8; ++e) afrag[kk][mo][e] = (__bf16)wp[e];
        }
    }

    // ---- feat[j] fragments in f32 registers. Once per block. ----
    float fjr[2][2][8];                 // [n][kk][e]
#pragma unroll
    for (int n = 0; n < 2; ++n) {
        const float* fjrow = feat + (jw + n * 16 + l15) * NF;
#pragma unroll
        for (int kk = 0; kk < 2; ++kk)
#pragma unroll
            for (int e = 0; e < 8; ++e)
                fjr[n][kk][e] = fjrow[kk * 32 + lg * 8 + e];
    }

    // ---- adjacency-channel weights + bias (o = mo*16 + lg*4 + r). Once. ----
    float wl[4][4], bv[4][4];
#pragma unroll
    for (int mo = 0; mo < 4; ++mo) {
        const float* bp = b + mo * 16 + lg * 4;
#pragma unroll
        for (int r = 0; r < 4; ++r) {
            bv[mo][r] = bp[r];
            wl[mo][r] = W[(mo * 16 + lg * 4 + r) * FIN + NF];
        }
    }

    // ---- i loop ----
    for (int ii = 0; ii < TI; ++ii) {
        const int i = i0 + ii;

        float fi[2][8];
#pragma unroll
        for (int kk = 0; kk < 2; ++kk) {
            const float* fp = feat + i * NF + kk * 32 + lg * 8;
#pragma unroll
            for (int e = 0; e < 8; ++e) fi[kk][e] = fp[e];
        }

        f32x4 acc[4][2];                // [mo][n], bias folded into init
#pragma unroll
        for (int mo = 0; mo < 4; ++mo)
#pragma unroll
            for (int n = 0; n < 2; ++n)
#pragma unroll
                for (int r = 0; r < 4; ++r)
                    acc[mo][n][r] = bv[mo][r];

#pragma unroll
        for (int n = 0; n < 2; ++n) {
#pragma unroll
            for (int kk = 0; kk < 2; ++kk) {
                bf16x8 bfrag;
#pragma unroll
                for (int e = 0; e < 8; ++e)
                    bfrag[e] = (__bf16)fabsf(fjr[n][kk][e] - fi[kk][e]);
#pragma unroll
                for (int mo = 0; mo < 4; ++mo)
                    acc[mo][n] = __builtin_amdgcn_mfma_f32_16x16x32_bf16(
                        afrag[kk][mo], bfrag, acc[mo][n], 0, 0, 0);
            }
        }

#pragma unroll
        for (int n = 0; n < 2; ++n) {
            const int j = jw + n * 16 + l15;
            const float av = adj[(size_t)i * N_NODES + j];
            float* op = out + ((size_t)i * N_NODES + j) * NOUT + lg * 4;
#pragma unroll
            for (int mo = 0; mo < 4; ++mo) {
                f32x4 v;
#pragma unroll
                for (int r = 0; r < 4; ++r)
                    v[r] = acc[mo][n][r] + av * wl[mo][r];
                *reinterpret_cast<f32x4*>(op + mo * 16) = v;
            }
        }
    }
}

extern "C" void kernel_launch(void* const* d_in, const int* in_sizes, int n_in,
                              void* d_out, int out_size, void* d_ws, size_t ws_size,
                              hipStream_t stream) {
    const float* feat = (const float*)d_in[0];   // [1536][64]
    const float* adj  = (const float*)d_in[1];   // [1536][1536]
    const float* W    = (const float*)d_in[2];   // [64][65]
    const float* b    = (const float*)d_in[3];   // [64]
    float* out = (float*)d_out;                  // [1536*1536][64]

    dim3 grid(N_NODES / 128, N_NODES / TI);
    dim3 block(256);
    edge_gcn_mfma<<<grid, block, 0, stream>>>(feat, adj, W, b, out);
}

// Round 4
// 148.630 us; speedup vs baseline: 1.8633x; 1.3163x over previous
//
#include <hip/hip_runtime.h>
#include <hip/hip_bf16.h>

#define N_NODES 1536
#define NF 64
#define NOUT 64
#define FIN 65
#define TI 8

typedef __bf16 bf16x8 __attribute__((ext_vector_type(8)));
typedef float f32x4 __attribute__((ext_vector_type(4)));

// One block: TI=8 i-rows x 128 j-cols. Swapped-operand MFMA
//   D[o][j] = sum_k W[o][k] * |feat[j][k]-feat[i][k]|
// Epilogue transposes each wave's 32j x 64o tile through wave-private
// XOR-swizzled LDS so global stores are 1 KB lane-contiguous (full 128B
// lines -> no write-allocate RMW traffic, which cost ~600 MB of fetch).
__global__ __launch_bounds__(256, 2)
void edge_gcn_mfma(const float* __restrict__ feat,
                   const float* __restrict__ adj,
                   const float* __restrict__ W,
                   const float* __restrict__ b,
                   float* __restrict__ out)
{
    const int tid  = threadIdx.x;
    const int lane = tid & 63;
    const int wv   = tid >> 6;          // wave 0..3
    const int l15  = lane & 15;
    const int lg   = lane >> 4;         // 0..3

    const int i0 = blockIdx.y * TI;
    const int j0 = blockIdx.x * 128;
    const int jw = j0 + wv * 32;        // this wave's 32 j's

    // 2 buffers x 4 waves x 2048 floats (8 KB) = 64 KB
    __shared__ float lds[16384];

    // ---- A fragments (W): once per block ----
    bf16x8 afrag[2][4];                 // [kk][mo]
#pragma unroll
    for (int kk = 0; kk < 2; ++kk) {
#pragma unroll
        for (int mo = 0; mo < 4; ++mo) {
            const float* wp = W + (mo * 16 + l15) * FIN + kk * 32 + lg * 8;
#pragma unroll
            for (int e = 0; e < 8; ++e) afrag[kk][mo][e] = (__bf16)wp[e];
        }
    }

    // ---- feat[j] fragments: once per block ----
    float fjr[2][2][8];                 // [n][kk][e]
#pragma unroll
    for (int n = 0; n < 2; ++n) {
        const float* fjrow = feat + (jw + n * 16 + l15) * NF;
#pragma unroll
        for (int kk = 0; kk < 2; ++kk)
#pragma unroll
            for (int e = 0; e < 8; ++e)
                fjr[n][kk][e] = fjrow[kk * 32 + lg * 8 + e];
    }

    // ---- adjacency-channel weights + bias (o = mo*16 + lg*4 + r): once ----
    float wl[4][4], bv[4][4];
#pragma unroll
    for (int mo = 0; mo < 4; ++mo) {
        const float* bp = b + mo * 16 + lg * 4;
#pragma unroll
        for (int r = 0; r < 4; ++r) {
            bv[mo][r] = bp[r];
            wl[mo][r] = W[(mo * 16 + lg * 4 + r) * FIN + NF];
        }
    }

    // ---- i loop ----
    for (int ii = 0; ii < TI; ++ii) {
        const int i = i0 + ii;
        float* lbase = lds + (ii & 1) * 8192 + wv * 2048;

        float fi[2][8];
#pragma unroll
        for (int kk = 0; kk < 2; ++kk) {
            const float* fp = feat + i * NF + kk * 32 + lg * 8;
#pragma unroll
            for (int e = 0; e < 8; ++e) fi[kk][e] = fp[e];
        }

        f32x4 acc[4][2];                // [mo][n], bias folded into init
#pragma unroll
        for (int mo = 0; mo < 4; ++mo)
#pragma unroll
            for (int n = 0; n < 2; ++n)
#pragma unroll
                for (int r = 0; r < 4; ++r)
                    acc[mo][n][r] = bv[mo][r];

#pragma unroll
        for (int n = 0; n < 2; ++n) {
#pragma unroll
            for (int kk = 0; kk < 2; ++kk) {
                bf16x8 bfrag;
#pragma unroll
                for (int e = 0; e < 8; ++e)
                    bfrag[e] = (__bf16)fabsf(fjr[n][kk][e] - fi[kk][e]);
#pragma unroll
                for (int mo = 0; mo < 4; ++mo)
                    acc[mo][n] = __builtin_amdgcn_mfma_f32_16x16x32_bf16(
                        afrag[kk][mo], bfrag, acc[mo][n], 0, 0, 0);
            }
        }

        // ---- epilogue A: finalize + write transposed tile into LDS ----
        // tile T[j(32)][o(64)], float off = j*64 + (o ^ ((j&7)<<2))
#pragma unroll
        for (int n = 0; n < 2; ++n) {
            const int jrow = n * 16 + l15;     // j within wave tile
            const float av = adj[(size_t)i * N_NODES + jw + jrow];
#pragma unroll
            for (int mo = 0; mo < 4; ++mo) {
                f32x4 v;
#pragma unroll
                for (int r = 0; r < 4; ++r)
                    v[r] = acc[mo][n][r] + av * wl[mo][r];
                const int swz = (mo * 16 + lg * 4) ^ ((l15 & 7) << 2);
                *reinterpret_cast<f32x4*>(lbase + jrow * 64 + swz) = v;
            }
        }

        // ---- epilogue B: read lane-contiguous, 1 KB stores ----
#pragma unroll
        for (int t = 0; t < 8; ++t) {
            const int jr = t * 4 + (lane >> 4);
            const int oo = (lane & 15) * 4;
            f32x4 v = *reinterpret_cast<const f32x4*>(
                lbase + jr * 64 + (oo ^ ((jr & 7) << 2)));
            float* op = out + ((size_t)i * N_NODES + jw + jr) * NOUT + oo;
            *reinterpret_cast<f32x4*>(op) = v;
        }
    }
}

extern "C" void kernel_launch(void* const* d_in, const int* in_sizes, int n_in,
                              void* d_out, int out_size, void* d_ws, size_t ws_size,
                              hipStream_t stream) {
    const float* feat = (const float*)d_in[0];   // [1536][64]
    const float* adj  = (const float*)d_in[1];   // [1536][1536]
    const float* W    = (const float*)d_in[2];   // [64][65]
    const float* b    = (const float*)d_in[3];   // [64]
    float* out = (float*)d_out;                  // [1536*1536][64]

    dim3 grid(N_NODES / 128, N_NODES / TI);
    dim3 block(256);
    edge_gcn_mfma<<<grid, block, 0, stream>>>(feat, adj, W, b, out);
}